// Round 3
// baseline (314.733 us; speedup 1.0000x reference)
//
#include <hip/hip_runtime.h>
#include <cmath>

#define SEQ 32
#define BB 1024
#define II 2048
#define OO 1024

typedef unsigned short ushortt;

// ---------------- build idx row (ordered) + rev scatter (rcnt pre-zeroed) ----------------
__global__ void build_idx_rev(const float* __restrict__ x, ushortt* __restrict__ idxArr,
                              int* __restrict__ cntArr, int* __restrict__ rcnt,
                              ushortt* __restrict__ rev) {
  int b = blockIdx.x;
  int lane = threadIdx.x;  // 64 threads = 1 wave
  __shared__ ushortt sIdx[256];
  const float* row = x + (long)b * II;
  int base = 0;
  for (int c = 0; c < II / 64; ++c) {
    float val = row[c * 64 + lane];
    unsigned long long m = __ballot(val != 0.0f);
    if (val != 0.0f) {
      int pos = base + __popcll(m & ((1ull << lane) - 1ull));
      if (pos < 256) {
        idxArr[(b << 8) + pos] = (ushortt)(c * 64 + lane);
        sIdx[pos] = (ushortt)(c * 64 + lane);
      }
    }
    base += __popcll(m);
  }
  int cnt = base < 256 ? base : 256;
  if (lane == 0) cntArr[b] = cnt;
  __syncthreads();
  for (int j = lane; j < cnt; j += 64) {
    int i = sIdx[j];
    int pos = atomicAdd(&rcnt[i], 1);
    if (pos < 128) rev[((long)i << 7) + pos] = (ushortt)b;
  }
}

// ---------------- idxT interleaved ushort4 groups: [j/4][b][j%4] (pad II) + nvec ----------------
__global__ void build_idxT(const ushortt* __restrict__ idxArr, const int* __restrict__ cntArr,
                           ushortt* __restrict__ idxT, const int* __restrict__ rcnt,
                           float* __restrict__ nvec) {
  int id = blockIdx.x * 256 + threadIdx.x;
  int j = id >> 10, b = id & 1023;
  ushortt v = (j < cntArr[b]) ? idxArr[(b << 8) + j] : (ushortt)II;
  idxT[(j >> 2) * 4096 + (b << 2) + (j & 3)] = v;
  if (id < II) nvec[id] = (float)rcnt[id];
}

// ---------------- fp32 transpose: dst[c*R+r] = src[r*C+c], src R x C ----------------
__global__ void transpose_f32(const float* __restrict__ src, float* __restrict__ dst,
                              int R, int C) {
  __shared__ float t[32][33];
  int c0 = blockIdx.x * 32, r0 = blockIdx.y * 32;
  int tx = threadIdx.x, ty = threadIdx.y;
#pragma unroll
  for (int k = 0; k < 4; k++)
    t[ty + k * 8][tx] = src[(long)(r0 + ty + k * 8) * C + c0 + tx];
  __syncthreads();
#pragma unroll
  for (int k = 0; k < 4; k++)
    dst[(long)(c0 + ty + k * 8) * R + r0 + tx] = t[tx][ty + k * 8];
}

// ---------------- dual transpose for z/v ([O][B] -> [B][O]) ----------------
__global__ void transpose2_f32(const float* __restrict__ zC, const float* __restrict__ vC,
                               float* __restrict__ oz, float* __restrict__ ov) {
  __shared__ float t[32][33];
  const float* src = blockIdx.z ? vC : zC;
  float* dst = blockIdx.z ? ov : oz;
  int c0 = blockIdx.x * 32, r0 = blockIdx.y * 32;  // src is OO x BB
  int tx = threadIdx.x, ty = threadIdx.y;
#pragma unroll
  for (int k = 0; k < 4; k++)
    t[ty + k * 8][tx] = src[(long)(r0 + ty + k * 8) * BB + c0 + tx];
  __syncthreads();
#pragma unroll
  for (int k = 0; k < 4; k++)
    dst[(long)(c0 + ty + k * 8) * OO + r0 + tx] = t[tx][ty + k * 8];
}

// ---------------- S0[b][o] = sum over act(b) of wT[i][o]; snArr[b] (exact ints) ----------------
__global__ __launch_bounds__(256) void s0_kernel(
    const float* __restrict__ wT, const ushortt* __restrict__ idxArr,
    const int* __restrict__ cntArr, const float* __restrict__ nvec,
    float* __restrict__ S0, float* __restrict__ snArr) {
  int b = blockIdx.x, tid = threadIdx.x, lane = tid & 63, wave = tid >> 6;
  __shared__ ushortt sIdx[256];
  __shared__ float sred[4];
  sIdx[tid] = idxArr[(b << 8) + tid];
  __syncthreads();
  int cnt = cntArr[b];
  const float4* wT4 = (const float4*)wT;
  float4 acc; acc.x = acc.y = acc.z = acc.w = 0.f;
  int j = 0;
  for (; j + 4 <= cnt; j += 4) {
    int i0 = sIdx[j], i1 = sIdx[j + 1], i2 = sIdx[j + 2], i3 = sIdx[j + 3];
    float4 a0 = wT4[(i0 << 8) + tid];
    float4 a1 = wT4[(i1 << 8) + tid];
    float4 a2 = wT4[(i2 << 8) + tid];
    float4 a3 = wT4[(i3 << 8) + tid];
    acc.x += a0.x; acc.y += a0.y; acc.z += a0.z; acc.w += a0.w;
    acc.x += a1.x; acc.y += a1.y; acc.z += a1.z; acc.w += a1.w;
    acc.x += a2.x; acc.y += a2.y; acc.z += a2.z; acc.w += a2.w;
    acc.x += a3.x; acc.y += a3.y; acc.z += a3.z; acc.w += a3.w;
  }
  for (; j < cnt; ++j) {
    float4 a = wT4[((int)sIdx[j] << 8) + tid];
    acc.x += a.x; acc.y += a.y; acc.z += a.z; acc.w += a.w;
  }
  ((float4*)S0)[(b << 8) + tid] = acc;
  float sv = (tid < cnt) ? nvec[sIdx[tid]] : 0.f;
#pragma unroll
  for (int off = 32; off > 0; off >>= 1) sv += __shfl_xor(sv, off);
  if (lane == 0) sred[wave] = sv;
  __syncthreads();
  if (tid == 0) snArr[b] = sred[0] + sred[1] + sred[2] + sred[3];
}

// ---------------- full 32-step sim, one block per column ----------------
// Per-input state packed in float4 LDS: wan[i] = (w, a_masked, n_masked, scratch).
// .w lanes double as scatter scratch (Sfix = wan[b].w, SnuD = wan[1024+b].w,
// spike mL = wan[i].w) -- word-granular LDS atomics never collide with the
// b64+b32 partial writes of .xyz. Keeps LDS at 38.9 KB -> 4 blocks/CU (32 waves).
__global__ __launch_bounds__(512, 8) void snn_kernel(
    const float* __restrict__ w,
    const float* __restrict__ bias, const float* __restrict__ nvec,
    const ushortt* __restrict__ idxT, const int* __restrict__ cntArr,
    const float* __restrict__ snArr, const float* __restrict__ S0T,
    const int* __restrict__ rcnt, const ushortt* __restrict__ rev,
    const ushortt* __restrict__ idxArr,
    float* __restrict__ zC, float* __restrict__ vC, float* __restrict__ outw,
    float dec) {
  int o = blockIdx.x, tid = threadIdx.x, lane = tid & 63, wave = tid >> 6;
  __shared__ float4 wan[II + 1];
  __shared__ float SAD[BB];
  __shared__ ushortt sList[BB];
  __shared__ int sCnt, sFlag, cFlag;
  float* wf = (float*)wan;

#pragma unroll
  for (int q = 0; q < 4; ++q) {
    int i = q * 512 + tid;
    wan[i] = make_float4(w[(long)o * II + i], 0.f, nvec[i], 0.f);
  }
#pragma unroll
  for (int k = 0; k < 2; ++k) SAD[k * 512 + tid] = 0.f;
  if (tid == 0) {
    sFlag = 0; cFlag = 0; sCnt = 0;
    wan[II] = make_float4(0.f, 0.f, 0.f, 0.f);
  }

  double S[2];
  float Snu[2], SA[2], v4[2], zk[2];
#pragma unroll
  for (int k = 0; k < 2; ++k) {
    int b = k * 512 + tid;
    S[k] = (double)S0T[(long)o * BB + b];  // coalesced
    Snu[k] = snArr[b];
    SA[k] = 0.f;
    v4[k] = 0.f; zk[k] = 0.f;
  }
  int jmax[2];
#pragma unroll
  for (int k = 0; k < 2; ++k) {
    int c = cntArr[k * 512 + wave * 64 + lane];
#pragma unroll
    for (int off = 32; off > 0; off >>= 1) c = max(c, __shfl_xor(c, off));
    jmax[k] = c;
  }
  float bo = bias[o];
  unsigned clipped = 0;
  float p = 1.f, u = 1.f;
  __syncthreads();

  for (int t = 0; t < SEQ; ++t) {
    p *= dec; u *= dec; u += 1.f;
    float spre = u - p;
    // phase A: z/v from S
    int local = 0;
#pragma unroll
    for (int k = 0; k < 2; ++k) {
      float zin = (float)S[k] + bo;
      float nv = v4[k] * dec + zin;
      float z = (nv >= 1.f) ? 1.f : 0.f;
      nv = nv * (1.f - z);
      v4[k] = nv; zk[k] = z;
      if (z != 0.f) local = 1;
    }
    if (local) sFlag = 1;
    if (tid == 0) sCnt = 0;
    __syncthreads();
    int spk = sFlag;

    if (!spk) {
      // quiet step: per-i recurrence (b128 read, b64+b32 write) + clip scatter into .w
#pragma unroll
      for (int q = 0; q < 4; ++q) {
        int i = q * 512 + tid;
        bool already = (clipped >> q) & 1u;
        float n = 0.f, atn = 0.f, fix = 0.f;
        bool cl = false;
        if (!already) {
          float4 tq = wan[i];
          n = tq.z;
          atn = dec * tq.y;
          float dw = -(1e-3f * (p * n + atn));
          float wold = tq.x;
          float pre = wold + dw;
          float wv = fminf(fmaxf(pre, -1.f), 1.f);
          cl = (pre <= -1.f);
          float ny, nz;
          if (cl) {
            clipped |= 1u << q;
            fix = (-1.f - wold) - dw;
            ny = 0.f; nz = 0.f;
          } else {
            ny = atn; nz = n;
          }
          *(float2*)&wan[i] = make_float2(wv, ny);  // .x,.y (never touches .w)
          ((float*)&wan[i])[2] = nz;                // .z
        }
        unsigned long long m = __ballot(cl);
        if (m) {
          if (lane == 0) cFlag = 1;
          while (m) {
            int src = __builtin_ctzll(m);
            m &= m - 1;
            int ii = __shfl(i, src);
            float fx = __shfl(fix, src);
            float mn = -__shfl(n, src);
            float ma = -__shfl(atn, src);
            int rc = rcnt[ii];
            const ushortt* rp = rev + ((long)ii << 7);
            for (int r = lane; r < rc; r += 64) {
              int b2 = rp[r];
              atomicAdd(&wf[(b2 << 2) + 3], fx);             // Sfix
              atomicAdd(&wf[((1024 + b2) << 2) + 3], mn);    // SnuD
              atomicAdd(&SAD[b2], ma);
            }
          }
        }
      }
      __syncthreads();
      float coefP = 1e-3f * p;
      if (cFlag) {
#pragma unroll
        for (int k = 0; k < 2; ++k) {
          int b = k * 512 + tid;
          float fx = wf[(b << 2) + 3];
          float snd = wf[((1024 + b) << 2) + 3];
          float sad = SAD[b];
          S[k] = S[k] - (double)coefP * (double)Snu[k]
                      - (double)1e-3f * (double)(dec * SA[k])
                      + (double)fx;
          SA[k] = dec * SA[k] + sad;
          Snu[k] = Snu[k] + snd;
          wf[(b << 2) + 3] = 0.f; wf[((1024 + b) << 2) + 3] = 0.f; SAD[b] = 0.f;
        }
      } else {
#pragma unroll
        for (int k = 0; k < 2; ++k) {
          S[k] = S[k] - (double)coefP * (double)Snu[k]
                      - (double)1e-3f * (double)(dec * SA[k]);
          SA[k] = dec * SA[k];
        }
      }
      if (tid == 0) { sFlag = 0; cFlag = 0; }
      __syncthreads();
    } else {
      // spike step: sList build (sCnt pre-zeroed), sparse mL scatter into .w
      // (.w is guaranteed 0 on entry), per-i b128 update (resets .w), re-gather.
#pragma unroll
      for (int k = 0; k < 2; ++k)
        if (zk[k] != 0.f) { int pos = atomicAdd(&sCnt, 1); sList[pos] = (ushortt)(k * 512 + tid); }
      __syncthreads();
      int ns = sCnt;
      for (int s = wave; s < ns; s += 8) {
        int b = sList[s];
        int cb = cntArr[b];
        const ushortt* ip = idxArr + (b << 8);
        for (int j = lane; j < cb; j += 64)
          atomicAdd(&wf[((int)ip[j] << 2) + 3], 1.f);  // mL
      }
      __syncthreads();
      float cv = (float)ns;
#pragma unroll
      for (int q = 0; q < 4; ++q) {
        int i = q * 512 + tid;
        float4 tq = wan[i];
        float mt = tq.w;
        float atn = dec * tq.y + mt;
        float n0 = nvec[i];  // true n (masked .z unusable here)
        float dw = 1e-3f * (p * cv + spre * mt) - 1e-3f * (p * n0 + atn);
        float pre = tq.x + dw;
        float wv = fminf(fmaxf(pre, -1.f), 1.f);
        bool cl = (pre <= -1.f);
        if (cl) clipped |= 1u << q; else clipped &= ~(1u << q);
        wan[i] = make_float4(wv, cl ? 0.f : atn, cl ? 0.f : n0, 0.f);  // .w=0 restores scratch
      }
      __syncthreads();  // wan final; mL/sList dead
      // re-gather S (double, element order preserved), SA, Snu via ushort4 idxT groups
      const ushort4* tpb = (const ushort4*)idxT;
#pragma unroll
      for (int k = 0; k < 2; ++k) {
        int b = k * 512 + tid;
        double s = 0.0;
        float sa = 0.f, sn = 0.f;
        int jm4 = (jmax[k] + 3) >> 2;
        const ushort4* tp = tpb + b;
        int g = 0;
        for (; g + 2 <= jm4; g += 2) {
          ushort4 u0 = tp[(g << 10)];
          ushort4 u1 = tp[((g + 1) << 10)];
          float4 a0 = wan[u0.x], a1 = wan[u0.y], a2 = wan[u0.z], a3 = wan[u0.w];
          s += (double)a0.x; s += (double)a1.x; s += (double)a2.x; s += (double)a3.x;
          sa += a0.y; sa += a1.y; sa += a2.y; sa += a3.y;
          sn += a0.z; sn += a1.z; sn += a2.z; sn += a3.z;
          float4 b0 = wan[u1.x], b1 = wan[u1.y], b2 = wan[u1.z], b3 = wan[u1.w];
          s += (double)b0.x; s += (double)b1.x; s += (double)b2.x; s += (double)b3.x;
          sa += b0.y; sa += b1.y; sa += b2.y; sa += b3.y;
          sn += b0.z; sn += b1.z; sn += b2.z; sn += b3.z;
        }
        for (; g < jm4; ++g) {
          ushort4 u0 = tp[(g << 10)];
          float4 a0 = wan[u0.x], a1 = wan[u0.y], a2 = wan[u0.z], a3 = wan[u0.w];
          s += (double)a0.x; s += (double)a1.x; s += (double)a2.x; s += (double)a3.x;
          sa += a0.y; sa += a1.y; sa += a2.y; sa += a3.y;
          sn += a0.z; sn += a1.z; sn += a2.z; sn += a3.z;
        }
        S[k] = s; SA[k] = sa; Snu[k] = sn;
        SAD[b] = 0.f;  // restore quiet-phase invariant
      }
      if (tid == 0) { sFlag = 0; cFlag = 0; }
      __syncthreads();
    }
  }

  __syncthreads();
  // coalesced outputs: w row-major; z/v column-major staging (transposed after)
#pragma unroll
  for (int q = 0; q < 4; ++q) outw[(long)o * II + q * 512 + tid] = wan[q * 512 + tid].x;
#pragma unroll
  for (int k = 0; k < 2; ++k) {
    int b = k * 512 + tid;
    zC[(long)o * BB + b] = zk[k];
    vC[(long)o * BB + b] = v4[k];
  }
}

extern "C" void kernel_launch(void* const* d_in, const int* in_sizes, int n_in,
                              void* d_out, int out_size, void* d_ws, size_t ws_size,
                              hipStream_t stream) {
  const float* x = (const float*)d_in[0];     // [B, I] {0,1} fp32
  const float* w = (const float*)d_in[1];     // [O, I] fp32
  const float* bias = (const float*)d_in[2];  // [O]
  float* out = (float*)d_out;                 // z[B,O] | v[B,O] | w[O,I]

  char* ws = (char*)d_ws;
  ushortt* idxArr = (ushortt*)(ws + 0);        // 512 KB
  int* cntArr = (int*)(ws + 524288);           // 4 KB
  ushortt* idxT = (ushortt*)(ws + 528384);     // 512 KB (interleaved ushort4 groups)
  float* nvec = (float*)(ws + 1052672);        // 8 KB
  float* snArr = (float*)(ws + 1060864);       // 4 KB
  int* rcnt = (int*)(ws + 1064960);            // 8 KB
  ushortt* rev = (ushortt*)(ws + 1073152);     // 512 KB
  float* wT = (float*)(ws + 1597440);          // 8 MB
  float* S0 = (float*)(ws + 9986048);          // 4 MB [B][O]
  float* S0T = (float*)(ws + 14180352);        // 4 MB [O][B]
  float* zC = (float*)(ws + 18374656);         // 4 MB
  float* vC = (float*)(ws + 22568960);         // 4 MB

  hipMemsetAsync(rcnt, 0, II * sizeof(int), stream);
  build_idx_rev<<<BB, 64, 0, stream>>>(x, idxArr, cntArr, rcnt, rev);
  build_idxT<<<1024, 256, 0, stream>>>(idxArr, cntArr, idxT, rcnt, nvec);
  // wT = w^T ([O][I] -> [I][O])
  transpose_f32<<<dim3(II / 32, OO / 32), dim3(32, 8), 0, stream>>>(w, wT, OO, II);
  // S0[b][o] + snArr[b], then S0T[o][b]
  s0_kernel<<<BB, 256, 0, stream>>>(wT, idxArr, cntArr, nvec, S0, snArr);
  transpose_f32<<<dim3(OO / 32, BB / 32), dim3(32, 8), 0, stream>>>(S0, S0T, BB, OO);

  const float dec = (float)exp(-0.05);  // shared decay (pre/post/mem)

  snn_kernel<<<OO, 512, 0, stream>>>(w, bias, nvec, idxT, cntArr, snArr, S0T,
                                     rcnt, rev, idxArr, zC, vC, out + 2 * BB * OO, dec);

  // z, v: [O][B] -> [B][O]
  transpose2_f32<<<dim3(BB / 32, OO / 32, 2), dim3(32, 8), 0, stream>>>(zC, vC, out, out + BB * OO);
}

// Round 4
// 285.596 us; speedup vs baseline: 1.1020x; 1.1020x over previous
//
#include <hip/hip_runtime.h>
#include <cmath>

#define SEQ 32
#define BB 1024
#define II 2048
#define OO 1024

typedef unsigned short ushortt;

// ---- build idx row (ordered) + idxT ushort4 groups [g][b] + rev scatter (rcnt pre-zeroed) ----
__global__ void build_idx_rev(const float* __restrict__ x, ushortt* __restrict__ idxArr,
                              int* __restrict__ cntArr, int* __restrict__ rcnt,
                              ushortt* __restrict__ rev, ushortt* __restrict__ idxT) {
  int b = blockIdx.x;
  int lane = threadIdx.x;  // 64 threads = 1 wave
  __shared__ ushortt sIdx[256];
  const float* row = x + (long)b * II;
  int base = 0;
  for (int c = 0; c < II / 64; ++c) {
    float val = row[c * 64 + lane];
    unsigned long long m = __ballot(val != 0.0f);
    if (val != 0.0f) {
      int pos = base + __popcll(m & ((1ull << lane) - 1ull));
      if (pos < 256) {
        idxArr[(b << 8) + pos] = (ushortt)(c * 64 + lane);
        sIdx[pos] = (ushortt)(c * 64 + lane);
      }
    }
    base += __popcll(m);
  }
  int cnt = base < 256 ? base : 256;  // uniform across lanes (base from full ballots)
  if (lane == 0) cntArr[b] = cnt;
  __syncthreads();
  // idxT group g = lane covers j = 4g..4g+3, padded with II
  {
    int j0 = lane * 4;
    ushort4 u;
    u.x = (j0 + 0 < cnt) ? sIdx[j0 + 0] : (ushortt)II;
    u.y = (j0 + 1 < cnt) ? sIdx[j0 + 1] : (ushortt)II;
    u.z = (j0 + 2 < cnt) ? sIdx[j0 + 2] : (ushortt)II;
    u.w = (j0 + 3 < cnt) ? sIdx[j0 + 3] : (ushortt)II;
    ((ushort4*)idxT)[(lane << 10) + b] = u;
  }
  for (int j = lane; j < cnt; j += 64) {
    int i = sIdx[j];
    int pos = atomicAdd(&rcnt[i], 1);
    if (pos < 128) rev[((long)i << 7) + pos] = (ushortt)b;
  }
}

// ---------------- dual transpose for z/v ([O][B] -> [B][O]) ----------------
__global__ void transpose2_f32(const float* __restrict__ zC, const float* __restrict__ vC,
                               float* __restrict__ oz, float* __restrict__ ov) {
  __shared__ float t[32][33];
  const float* src = blockIdx.z ? vC : zC;
  float* dst = blockIdx.z ? ov : oz;
  int c0 = blockIdx.x * 32, r0 = blockIdx.y * 32;  // src is OO x BB
  int tx = threadIdx.x, ty = threadIdx.y;
#pragma unroll
  for (int k = 0; k < 4; k++)
    t[ty + k * 8][tx] = src[(long)(r0 + ty + k * 8) * BB + c0 + tx];
  __syncthreads();
#pragma unroll
  for (int k = 0; k < 4; k++)
    dst[(long)(c0 + ty + k * 8) * OO + r0 + tx] = t[tx][ty + k * 8];
}

// ---------------- full 32-step sim, one block per column ----------------
// State in 3 separate fp32 LDS arrays (wL/aG/nG): random-index ds_read_b32 is
// near-conflict-free (2-way avg is free); packed float4 gathers were measured
// 27x worse on SQ_LDS_BANK_CONFLICT. Initial S/Snu computed by an in-LDS
// gather (replaces the former s0_kernel + 2 transposes). Index loads are
// coalesced ushort4 groups. LDS 37.4 KB -> 4 blocks/CU, 32 waves/CU.
__global__ __launch_bounds__(512, 8) void snn_kernel(
    const float* __restrict__ w, const float* __restrict__ bias,
    const ushortt* __restrict__ idxT, const int* __restrict__ cntArr,
    const int* __restrict__ rcnt, const ushortt* __restrict__ rev,
    const ushortt* __restrict__ idxArr,
    float* __restrict__ zC, float* __restrict__ vC, float* __restrict__ outw,
    float dec) {
  int o = blockIdx.x, tid = threadIdx.x, lane = tid & 63, wave = tid >> 6;
  __shared__ float shbuf[9219];
  __shared__ int sCnt, sFlag, cFlag;
  float* wL = shbuf;                    // [0..2048] live w (pad slot 2048 = 0)
  float* aG = shbuf + 2049;             // [0..2048] A, masked 0 when clipped
  float* nG = shbuf + 4098;             // [0..2048] n, masked 0 when clipped
  float* mL = shbuf + 6147;             // 2048 (spike phase)
  int* sList = (int*)(shbuf + 8195);    // 1024 (spike phase)
  float* Sfix = shbuf + 6147;           // 1024 (quiet phase, aliases mL lo)
  float* SnuD = shbuf + 7171;           // 1024 (quiet phase, aliases mL hi)
  float* SAD = shbuf + 8195;            // 1024 (quiet phase, aliases sList)

#pragma unroll
  for (int q = 0; q < 4; ++q) {
    int i = q * 512 + tid;
    wL[i] = w[(long)o * II + i];
    aG[i] = 0.f;
    nG[i] = (float)rcnt[i];
  }
#pragma unroll
  for (int k = 0; k < 2; ++k) {
    int b = k * 512 + tid;
    Sfix[b] = 0.f; SnuD[b] = 0.f; SAD[b] = 0.f;
  }
  if (tid == 0) {
    sFlag = 0; cFlag = 0;
    wL[II] = 0.f; aG[II] = 0.f; nG[II] = 0.f;
  }

  int jmax[2];
#pragma unroll
  for (int k = 0; k < 2; ++k) {
    int c = cntArr[k * 512 + wave * 64 + lane];
#pragma unroll
    for (int off = 32; off > 0; off >>= 1) c = max(c, __shfl_xor(c, off));
    jmax[k] = c;
  }
  float bo = bias[o];
  unsigned clipped = 0;
  bool everSpk = false;
  float p = 1.f, u = 1.f;
  __syncthreads();

  // initial gather: S = sum w, Snu = sum n over act(b) (replaces s0_kernel)
  const ushort4* tpb = (const ushort4*)idxT;
  double S[2];
  float Snu[2], SA[2], v4[2], zk[2];
#pragma unroll
  for (int k = 0; k < 2; ++k) {
    int b = k * 512 + tid;
    double s = 0.0;
    float sn = 0.f;
    int jm4 = (jmax[k] + 3) >> 2;
    const ushort4* tp = tpb + b;
    for (int g = 0; g < jm4; ++g) {
      ushort4 u0 = tp[(g << 10)];
      int a_ = u0.x, b_ = u0.y, c_ = u0.z, d_ = u0.w;
      s += (double)wL[a_]; s += (double)wL[b_]; s += (double)wL[c_]; s += (double)wL[d_];
      sn += nG[a_]; sn += nG[b_]; sn += nG[c_]; sn += nG[d_];
    }
    S[k] = s; Snu[k] = sn;
    SA[k] = 0.f; v4[k] = 0.f; zk[k] = 0.f;
  }

  for (int t = 0; t < SEQ; ++t) {
    p *= dec; u *= dec; u += 1.f;
    float spre = u - p;
    // phase A: z/v from S
    int local = 0;
#pragma unroll
    for (int k = 0; k < 2; ++k) {
      float zin = (float)S[k] + bo;
      float nv = v4[k] * dec + zin;
      float z = (nv >= 1.f) ? 1.f : 0.f;
      nv = nv * (1.f - z);
      v4[k] = nv; zk[k] = z;
      if (z != 0.f) local = 1;
    }
    if (local) sFlag = 1;
    __syncthreads();
    int spk = sFlag;

    if (!spk) {
      // quiet step: per-i recurrence + wave-cooperative clip scatter
#pragma unroll
      for (int q = 0; q < 4; ++q) {
        int i = q * 512 + tid;
        bool already = (clipped >> q) & 1u;
        float n = 0.f, atn = 0.f, fix = 0.f;
        bool cl = false;
        if (!already) {
          n = nG[i];
          atn = everSpk ? (dec * aG[i]) : 0.f;
          float dw = -(1e-3f * (p * n + atn));
          float wold = wL[i];
          float pre = wold + dw;
          float wv = fminf(fmaxf(pre, -1.f), 1.f);
          cl = (pre <= -1.f);
          if (cl) {
            clipped |= 1u << q;
            fix = (-1.f - wold) - dw;
            nG[i] = 0.f;
            if (everSpk) aG[i] = 0.f;
          } else if (everSpk) {
            aG[i] = atn;
          }
          wL[i] = wv;
        }
        unsigned long long m = __ballot(cl);
        if (m) {
          if (lane == 0) cFlag = 1;
          while (m) {
            int src = __builtin_ctzll(m);
            m &= m - 1;
            int ii = __shfl(i, src);
            float fx = __shfl(fix, src);
            float mn = -__shfl(n, src);
            float ma = -__shfl(atn, src);
            int rc = rcnt[ii];
            const ushortt* rp = rev + ((long)ii << 7);
            for (int r = lane; r < rc; r += 64) {
              int b2 = rp[r];
              atomicAdd(&Sfix[b2], fx);
              atomicAdd(&SnuD[b2], mn);
              if (everSpk) atomicAdd(&SAD[b2], ma);
            }
          }
        }
      }
      __syncthreads();
      float coefP = 1e-3f * p;
      if (cFlag) {
#pragma unroll
        for (int k = 0; k < 2; ++k) {
          int b = k * 512 + tid;
          S[k] = S[k] - (double)coefP * (double)Snu[k]
                      - (double)1e-3f * (double)(dec * SA[k])
                      + (double)Sfix[b];
          SA[k] = dec * SA[k] + SAD[b];
          Snu[k] = Snu[k] + SnuD[b];
          Sfix[b] = 0.f; SnuD[b] = 0.f; SAD[b] = 0.f;
        }
      } else {
#pragma unroll
        for (int k = 0; k < 2; ++k) {
          S[k] = S[k] - (double)coefP * (double)Snu[k]
                      - (double)1e-3f * (double)(dec * SA[k]);
          SA[k] = dec * SA[k];
        }
      }
      if (tid == 0) { sFlag = 0; cFlag = 0; }
      __syncthreads();
    } else {
      // spike step: exact update via mL, then one re-gather to re-sync aggregates
      everSpk = true;
      if (tid == 0) sCnt = 0;
      __syncthreads();
#pragma unroll
      for (int k = 0; k < 2; ++k)
        if (zk[k] != 0.f) { int pos = atomicAdd(&sCnt, 1); sList[pos] = k * 512 + tid; }
#pragma unroll
      for (int q = 0; q < 4; ++q) mL[q * 512 + tid] = 0.f;
      __syncthreads();
      int ns = sCnt;
      // sparse scatter: mL[i] += 1 over active index list of each spiking batch
      for (int s = wave; s < ns; s += 8) {
        int b = sList[s];
        int cb = cntArr[b];
        const ushortt* ip = idxArr + (b << 8);
        for (int j = lane; j < cb; j += 64)
          atomicAdd(&mL[ip[j]], 1.f);
      }
      __syncthreads();
      float cv = (float)ns;
#pragma unroll
      for (int q = 0; q < 4; ++q) {
        int i = q * 512 + tid;
        float mt = mL[i];
        float atn = dec * aG[i] + mt;
        float n = (float)rcnt[i];  // true n (nG may be masked)
        float dw = 1e-3f * (p * cv + spre * mt) - 1e-3f * (p * n + atn);
        float wold = wL[i];
        float pre = wold + dw;
        float wv = fminf(fmaxf(pre, -1.f), 1.f);
        bool cl = (pre <= -1.f);
        if (cl) clipped |= 1u << q; else clipped &= ~(1u << q);
        wL[i] = wv;
        aG[i] = cl ? 0.f : atn;
        nG[i] = cl ? 0.f : n;
      }
      __syncthreads();  // wL/aG/nG final; mL/sList dead
      // re-gather S (double, ascending-j order), SA, Snu via ushort4 idxT groups
#pragma unroll
      for (int k = 0; k < 2; ++k) {
        int b = k * 512 + tid;
        double s = 0.0;
        float sa = 0.f, sn = 0.f;
        int jm4 = (jmax[k] + 3) >> 2;
        const ushort4* tp = tpb + b;
        int g = 0;
        for (; g + 2 <= jm4; g += 2) {
          ushort4 u0 = tp[(g << 10)];
          ushort4 u1 = tp[((g + 1) << 10)];
          int a_ = u0.x, b_ = u0.y, c_ = u0.z, d_ = u0.w;
          s += (double)wL[a_]; sa += aG[a_]; sn += nG[a_];
          s += (double)wL[b_]; sa += aG[b_]; sn += nG[b_];
          s += (double)wL[c_]; sa += aG[c_]; sn += nG[c_];
          s += (double)wL[d_]; sa += aG[d_]; sn += nG[d_];
          int e_ = u1.x, f_ = u1.y, g_ = u1.z, h_ = u1.w;
          s += (double)wL[e_]; sa += aG[e_]; sn += nG[e_];
          s += (double)wL[f_]; sa += aG[f_]; sn += nG[f_];
          s += (double)wL[g_]; sa += aG[g_]; sn += nG[g_];
          s += (double)wL[h_]; sa += aG[h_]; sn += nG[h_];
        }
        for (; g < jm4; ++g) {
          ushort4 u0 = tp[(g << 10)];
          int a_ = u0.x, b_ = u0.y, c_ = u0.z, d_ = u0.w;
          s += (double)wL[a_]; sa += aG[a_]; sn += nG[a_];
          s += (double)wL[b_]; sa += aG[b_]; sn += nG[b_];
          s += (double)wL[c_]; sa += aG[c_]; sn += nG[c_];
          s += (double)wL[d_]; sa += aG[d_]; sn += nG[d_];
        }
        S[k] = s; SA[k] = sa; Snu[k] = sn;
      }
      // restore quiet-phase scatter invariant (region aliased by mL/sList)
#pragma unroll
      for (int k = 0; k < 2; ++k) {
        int b = k * 512 + tid;
        Sfix[b] = 0.f; SnuD[b] = 0.f; SAD[b] = 0.f;
      }
      if (tid == 0) { sFlag = 0; cFlag = 0; }
      __syncthreads();
    }
  }

  __syncthreads();
  // coalesced outputs: w row-major; z/v column-major staging (transposed after)
#pragma unroll
  for (int q = 0; q < 4; ++q) outw[(long)o * II + q * 512 + tid] = wL[q * 512 + tid];
#pragma unroll
  for (int k = 0; k < 2; ++k) {
    int b = k * 512 + tid;
    zC[(long)o * BB + b] = zk[k];
    vC[(long)o * BB + b] = v4[k];
  }
}

extern "C" void kernel_launch(void* const* d_in, const int* in_sizes, int n_in,
                              void* d_out, int out_size, void* d_ws, size_t ws_size,
                              hipStream_t stream) {
  const float* x = (const float*)d_in[0];     // [B, I] {0,1} fp32
  const float* w = (const float*)d_in[1];     // [O, I] fp32
  const float* bias = (const float*)d_in[2];  // [O]
  float* out = (float*)d_out;                 // z[B,O] | v[B,O] | w[O,I]

  char* ws = (char*)d_ws;
  ushortt* idxArr = (ushortt*)(ws + 0);        // 512 KB
  int* cntArr = (int*)(ws + 524288);           // 4 KB
  ushortt* idxT = (ushortt*)(ws + 528384);     // 512 KB (ushort4 groups [g][b])
  int* rcnt = (int*)(ws + 1052672);            // 8 KB
  ushortt* rev = (ushortt*)(ws + 1060864);     // 512 KB
  float* zC = (float*)(ws + 1585152);          // 4 MB
  float* vC = (float*)(ws + 5779456);          // 4 MB

  hipMemsetAsync(rcnt, 0, II * sizeof(int), stream);
  build_idx_rev<<<BB, 64, 0, stream>>>(x, idxArr, cntArr, rcnt, rev, idxT);

  const float dec = (float)exp(-0.05);  // shared decay (pre/post/mem)

  snn_kernel<<<OO, 512, 0, stream>>>(w, bias, idxT, cntArr, rcnt, rev, idxArr,
                                     zC, vC, out + 2 * BB * OO, dec);

  // z, v: [O][B] -> [B][O]
  transpose2_f32<<<dim3(BB / 32, OO / 32, 2), dim3(32, 8), 0, stream>>>(zC, vC, out, out + BB * OO);
}